// Round 1
// baseline (126.298 us; speedup 1.0000x reference)
//
#include <hip/hip_runtime.h>

#define HID 256
#define NSEQ 1024
#define NH 16
#define DH 4
#define NB 4
#define SCALEF 0.5f
#define HEADSZ (NB * NH * NSEQ * DH)   // 262144 floats per projection buffer

// ---------------------------------------------------------------------------
// Kernel 1: 1x1-conv projections (Wq/Wk/Wv @ input), written directly in the
// reference's non-standard rearranged view [B][H][N][D]:
//   flat c*N+pos  ==  d*(N*H) + n*H + h   =>  d=c>>4, n=(c&15)*64+pos>>4, h=pos&15
// ---------------------------------------------------------------------------
__global__ __launch_bounds__(256) void proj_kernel(
    const float* __restrict__ q, const float* __restrict__ k,
    const float* __restrict__ v, const float* __restrict__ Wq,
    const float* __restrict__ Wk, const float* __restrict__ Wv,
    float* __restrict__ ws)
{
    const int tid   = threadIdx.x;
    const int pos_l = tid & 63;
    int cb = tid >> 6;                       // wave index 0..3 (wave-uniform)
    cb = __builtin_amdgcn_readfirstlane(cb); // force SGPR -> scalar W loads
    const int p    = blockIdx.y;             // which projection
    const int b    = blockIdx.z;
    const int pos0 = blockIdx.x * 64;

    const float* in = (p == 0) ? q : (p == 1) ? k : v;
    const float* W  = (p == 0) ? Wq : (p == 1) ? Wk : Wv;
    float* dst = ws + (size_t)p * HEADSZ;

    __shared__ float lds_in[64][64];         // 16 KB input tile

    float acc[16];
#pragma unroll
    for (int j = 0; j < 16; ++j) acc[j] = 0.f;

    const float* inb = in + (size_t)b * HID * NSEQ;

    for (int chunk = 0; chunk < 4; ++chunk) {
        const int i0 = chunk * 64;
        // stage 64 input channels x 64 positions (coalesced)
#pragma unroll
        for (int t = 0; t < 16; ++t) {
            int e = tid + t * 256;
            int r = e >> 6, pp = e & 63;
            lds_in[r][pp] = inb[(i0 + r) * NSEQ + pos0 + pp];
        }
        __syncthreads();
#pragma unroll
        for (int i8 = 0; i8 < 64; i8 += 8) {
            float x[8];
#pragma unroll
            for (int j = 0; j < 8; ++j) x[j] = lds_in[i8 + j][pos_l];
#pragma unroll
            for (int kk = 0; kk < 16; ++kk) {
                const float* wr = W + (cb * 16 + kk) * HID + i0 + i8;
#pragma unroll
                for (int j = 0; j < 8; ++j)
                    acc[kk] = fmaf(wr[j], x[j], acc[kk]);
            }
        }
        __syncthreads();
    }

    const int pos_g = pos0 + pos_l;
    const int h     = pos_g & 15;
    const int nsub  = pos_g >> 4;
#pragma unroll
    for (int kk = 0; kk < 16; ++kk) {
        int c = cb * 16 + kk;
        int d = c >> 4;
        int n = (c & 15) * 64 + nsub;
        dst[(((size_t)b * NH + h) * NSEQ + n) * DH + d] = acc[kk];
    }
}

// ---------------------------------------------------------------------------
// Kernel 2: attention. One wave per query row. K/V head slice staged in LDS
// as float4[1024]; 16 key positions per lane held in registers; wave-parallel
// softmax reductions. Bias is the 256 MB HBM stream -> nontemporal loads.
// Output written as X2[b][h*4+d][n] (the transposed view kernel 3 consumes).
// ---------------------------------------------------------------------------
__global__ __launch_bounds__(256) void attn_kernel(
    const float* __restrict__ bias, const float* __restrict__ ws,
    float* __restrict__ x2)
{
    const int tid  = threadIdx.x;
    const int lane = tid & 63;
    const int wave = tid >> 6;
    const int h    = blockIdx.y;
    const int b    = blockIdx.z;
    const int n0   = blockIdx.x * 64;

    const float4* Qh = (const float4*)(ws);
    const float4* Kh = (const float4*)(ws + (size_t)1 * HEADSZ);
    const float4* Vh = (const float4*)(ws + (size_t)2 * HEADSZ);

    __shared__ float4 ldsK[NSEQ];   // 16 KB
    __shared__ float4 ldsV[NSEQ];   // 16 KB

    const int headbase = (b * NH + h) * NSEQ;
    for (int i = tid; i < NSEQ; i += 256) {
        ldsK[i] = Kh[headbase + i];
        ldsV[i] = Vh[headbase + i];
    }
    __syncthreads();

    const float* biash = bias + (size_t)(b * NH + h) * NSEQ * NSEQ;

    for (int r = 0; r < 16; ++r) {
        const int n = n0 + wave * 16 + r;
        const float4 q4 = Qh[headbase + n];
        const float* brow = biash + (size_t)n * NSEQ;

        float s[16];
        float mx = -1e30f;
#pragma unroll
        for (int j = 0; j < 16; ++j) {
            int m = j * 64 + lane;
            float4 k4 = ldsK[m];
            float dot = q4.x * k4.x + q4.y * k4.y + q4.z * k4.z + q4.w * k4.w;
            s[j] = fmaf(dot, SCALEF, __builtin_nontemporal_load(brow + m));
            mx = fmaxf(mx, s[j]);
        }
#pragma unroll
        for (int off = 32; off > 0; off >>= 1)
            mx = fmaxf(mx, __shfl_xor(mx, off, 64));

        float sum = 0.f, o0 = 0.f, o1 = 0.f, o2 = 0.f, o3 = 0.f;
#pragma unroll
        for (int j = 0; j < 16; ++j) {
            int m = j * 64 + lane;
            float pexp = __expf(s[j] - mx);
            sum += pexp;
            float4 v4 = ldsV[m];
            o0 = fmaf(pexp, v4.x, o0);
            o1 = fmaf(pexp, v4.y, o1);
            o2 = fmaf(pexp, v4.z, o2);
            o3 = fmaf(pexp, v4.w, o3);
        }
#pragma unroll
        for (int off = 32; off > 0; off >>= 1) {
            sum += __shfl_xor(sum, off, 64);
            o0  += __shfl_xor(o0, off, 64);
            o1  += __shfl_xor(o1, off, 64);
            o2  += __shfl_xor(o2, off, 64);
            o3  += __shfl_xor(o3, off, 64);
        }
        float inv = 1.f / sum;
        float val = (lane == 0) ? o0 : (lane == 1) ? o1 : (lane == 2) ? o2 : o3;
        if (lane < 4) {
            x2[((size_t)b * (NH * DH) + h * DH + lane) * NSEQ + n] = val * inv;
        }
    }
}

// ---------------------------------------------------------------------------
// Kernel 3: output 1x1 conv + BatchNorm1d(eval) + LeakyReLU(0.2).
// 8 output channels per block; Wo/bn params are blockIdx-uniform -> scalar.
// ---------------------------------------------------------------------------
__global__ __launch_bounds__(256) void out_kernel(
    const float* __restrict__ x2, const float* __restrict__ Wo,
    const float* __restrict__ bo, const float* __restrict__ gamma,
    const float* __restrict__ beta, const float* __restrict__ rmean,
    const float* __restrict__ rvar, float* __restrict__ out)
{
    const int pos = blockIdx.x * 256 + threadIdx.x;
    const int o0  = blockIdx.y * 8;
    const int b   = blockIdx.z;

    float acc[8];
#pragma unroll
    for (int j = 0; j < 8; ++j) acc[j] = 0.f;

    const float* xb = x2 + (size_t)b * (NH * DH) * NSEQ;
#pragma unroll 8
    for (int c = 0; c < NH * DH; ++c) {
        float x = xb[c * NSEQ + pos];
#pragma unroll
        for (int j = 0; j < 8; ++j)
            acc[j] = fmaf(Wo[(o0 + j) * (NH * DH) + c], x, acc[j]);
    }
#pragma unroll
    for (int j = 0; j < 8; ++j) {
        int o = o0 + j;
        float inv = rsqrtf(rvar[o] + 1e-5f);
        float y = acc[j] + bo[o];
        y = (y - rmean[o]) * (gamma[o] * inv) + beta[o];
        y = (y > 0.f) ? y : 0.2f * y;
        out[((size_t)b * HID + o) * NSEQ + pos] = y;
    }
}

extern "C" void kernel_launch(void* const* d_in, const int* in_sizes, int n_in,
                              void* d_out, int out_size, void* d_ws, size_t ws_size,
                              hipStream_t stream) {
    const float* q     = (const float*)d_in[0];
    const float* k     = (const float*)d_in[1];
    const float* v     = (const float*)d_in[2];
    const float* bias  = (const float*)d_in[3];
    const float* Wq    = (const float*)d_in[4];
    const float* Wk    = (const float*)d_in[5];
    const float* Wv    = (const float*)d_in[6];
    const float* Wo    = (const float*)d_in[7];
    const float* bo    = (const float*)d_in[8];
    const float* gamma = (const float*)d_in[9];
    const float* beta  = (const float*)d_in[10];
    const float* rmean = (const float*)d_in[11];
    const float* rvar  = (const float*)d_in[12];

    float* ws = (float*)d_ws;                 // 3 proj buffers + X2 = 4 MB
    float* x2 = ws + (size_t)3 * HEADSZ;
    float* out = (float*)d_out;

    proj_kernel<<<dim3(NSEQ / 64, 3, NB), 256, 0, stream>>>(q, k, v, Wq, Wk, Wv, ws);
    attn_kernel<<<dim3(NSEQ / 64, NH, NB), 256, 0, stream>>>(bias, ws, x2);
    out_kernel<<<dim3(NSEQ / 256, HID / 8, NB), 256, 0, stream>>>(
        x2, Wo, bo, gamma, beta, rmean, rvar, out);
}